// Round 5
// baseline (24191.263 us; speedup 1.0000x reference)
//
#include <hip/hip_runtime.h>
#include <hip/hip_bf16.h>

// B=64, S=2048, WIN=50, E=128, H=256, G=4H=1024.
#define B_ 64
#define S_ 2048
#define W_ 50
#define E_ 128
#define H_ 256
#define G_ 1024
#define NB_ 4            // blocks cooperating per batch
#define TPB_ 512         // threads per lstm block

typedef unsigned short u16;
typedef unsigned int u32;

// Module-global scratch (BSS; d_ws untrusted). Proven working in round 4.
__device__ int g_mode;                          // 0 = bf16 buffers, 1 = fp32 buffers
__device__ u16 g_WihT[E_ * G_];                 // [e][4u+q] = Wih[q*H+u][e]  (bf16)
__device__ u16 g_Whh[G_ * H_];                  // row-major [G][H] canonical bf16
__device__ u16 g_xg[(size_t)B_ * S_ * G_];      // [b][quarter][s][256 cols], bf16, biases folded
__device__ u32 g_hx[2][B_][H_ / 2];             // h exchange: bf16 pairs, double-buffered
__device__ int g_cnt[B_];                       // per-batch monotonic post counter

__device__ __forceinline__ float b2f(u16 u) {
    union { u32 i; float f; } v;
    v.i = ((u32)u) << 16;
    return v.f;
}
__device__ __forceinline__ u16 f2b(float f) {
    __hip_bfloat16 h = __float2bfloat16(f);
    return *reinterpret_cast<u16*>(&h);
}
__device__ __forceinline__ float ldin(int mode, const void* p, size_t i) {
    return mode ? ((const float*)p)[i] : b2f(((const u16*)p)[i]);
}
__device__ __forceinline__ float clamp30(float x) {
    return fminf(fmaxf(x, -30.0f), 30.0f);      // transparent; squashes NaN
}
__device__ __forceinline__ float sigmoidf_(float x) { return 1.0f / (1.0f + __expf(-x)); }
__device__ __forceinline__ float tanhf_(float x) {
    float e = __expf(2.0f * x);
    return 1.0f - 2.0f / (e + 1.0f);
}

// ---------- K0: dtype sniffer (validated round 4) ----------
__global__ void sniff_kernel(const u16* __restrict__ wemb) {
    int sane = 0;
    for (int i = 0; i < 2048; ++i) {
        int ex = (wemb[i] >> 7) & 0xFF;
        if (ex == 0 || (ex >= 96 && ex <= 143)) ++sane;
    }
    g_mode = (sane >= 1900) ? 0 : 1;
}

// ---------- K0b: Wih gate-interleaved transpose ----------
__global__ __launch_bounds__(256) void transpose_wih(const void* __restrict__ src) {
    const int mode = g_mode;
    int i = blockIdx.x * 256 + threadIdx.x;          // i = e*G + 4u+q
    int e = i >> 10, r = i & 1023, u = r >> 2, q = r & 3;
    g_WihT[i] = f2b(ldin(mode, src, (size_t)((q << 15) + (u << 7) + e)));
}

// ---------- K0c: Whh canonicalize to bf16 (no transpose) + zero sync counters ----------
__global__ __launch_bounds__(256) void prep_whh(const void* __restrict__ src) {
    const int mode = g_mode;
    int i = blockIdx.x * 256 + threadIdx.x;          // i < G*H
    g_Whh[i] = f2b(ldin(mode, src, (size_t)i));
    if (blockIdx.x == 0 && threadIdx.x < B_) g_cnt[threadIdx.x] = 0;
}

// ---------- K1: fused embedding + input projection (store in per-quarter layout) ----------
__global__ __launch_bounds__(256) void xg_kernel(const void* __restrict__ pw,
                                                 const void* __restrict__ Wemb,
                                                 const void* __restrict__ bemb,
                                                 const void* __restrict__ bih,
                                                 const void* __restrict__ bhh) {
    const int mode = g_mode;
    const int t = threadIdx.x;
    const int m0 = blockIdx.x * 16;
    __shared__ float pw16[16][W_ + 2];
    __shared__ float Wl[E_ * 51];
    __shared__ __align__(16) float erow[16][E_];

    for (int i = t; i < E_ * W_; i += 256) {
        int e = i / W_, w = i - e * W_;
        Wl[e * 51 + w] = ldin(mode, Wemb, i);
    }
    for (int i = t; i < 16 * W_; i += 256) {
        int r = i / W_, w = i - r * W_;
        pw16[r][w] = ldin(mode, pw, (size_t)(m0 + r) * W_ + w);
    }
    __syncthreads();

#pragma unroll
    for (int i = 0; i < 8; ++i) {
        int idx = i * 256 + t;
        int r = idx >> 7, e = idx & 127;
        float a = ldin(mode, bemb, e);
        const float* wr = &Wl[e * 51];
#pragma unroll
        for (int w = 0; w < W_; ++w) a = fmaf(pw16[r][w], wr[w], a);
        erow[r][e] = fmaxf(a, 0.0f);
    }
    __syncthreads();

    const int g0 = 4 * t;
    float acc[16][4];
    {
        float b0 = ldin(mode, bih, t) + ldin(mode, bhh, t);
        float b1 = ldin(mode, bih, H_ + t) + ldin(mode, bhh, H_ + t);
        float b2 = ldin(mode, bih, 2 * H_ + t) + ldin(mode, bhh, 2 * H_ + t);
        float b3 = ldin(mode, bih, 3 * H_ + t) + ldin(mode, bhh, 3 * H_ + t);
#pragma unroll
        for (int r = 0; r < 16; ++r) { acc[r][0] = b0; acc[r][1] = b1; acc[r][2] = b2; acc[r][3] = b3; }
    }
    for (int e = 0; e < E_; e += 4) {
        ushort4 w0 = *(const ushort4*)(g_WihT + (size_t)(e + 0) * G_ + g0);
        ushort4 w1 = *(const ushort4*)(g_WihT + (size_t)(e + 1) * G_ + g0);
        ushort4 w2 = *(const ushort4*)(g_WihT + (size_t)(e + 2) * G_ + g0);
        ushort4 w3 = *(const ushort4*)(g_WihT + (size_t)(e + 3) * G_ + g0);
        float f00 = b2f(w0.x), f01 = b2f(w0.y), f02 = b2f(w0.z), f03 = b2f(w0.w);
        float f10 = b2f(w1.x), f11 = b2f(w1.y), f12 = b2f(w1.z), f13 = b2f(w1.w);
        float f20 = b2f(w2.x), f21 = b2f(w2.y), f22 = b2f(w2.z), f23 = b2f(w2.w);
        float f30 = b2f(w3.x), f31 = b2f(w3.y), f32 = b2f(w3.z), f33 = b2f(w3.w);
#pragma unroll
        for (int r = 0; r < 16; ++r) {
            float4 ev = *(const float4*)&erow[r][e];
            acc[r][0] = fmaf(ev.x, f00, acc[r][0]); acc[r][1] = fmaf(ev.x, f01, acc[r][1]);
            acc[r][2] = fmaf(ev.x, f02, acc[r][2]); acc[r][3] = fmaf(ev.x, f03, acc[r][3]);
            acc[r][0] = fmaf(ev.y, f10, acc[r][0]); acc[r][1] = fmaf(ev.y, f11, acc[r][1]);
            acc[r][2] = fmaf(ev.y, f12, acc[r][2]); acc[r][3] = fmaf(ev.y, f13, acc[r][3]);
            acc[r][0] = fmaf(ev.z, f20, acc[r][0]); acc[r][1] = fmaf(ev.z, f21, acc[r][1]);
            acc[r][2] = fmaf(ev.z, f22, acc[r][2]); acc[r][3] = fmaf(ev.z, f23, acc[r][3]);
            acc[r][0] = fmaf(ev.w, f30, acc[r][0]); acc[r][1] = fmaf(ev.w, f31, acc[r][1]);
            acc[r][2] = fmaf(ev.w, f32, acc[r][2]); acc[r][3] = fmaf(ev.w, f33, acc[r][3]);
        }
    }
#pragma unroll
    for (int r = 0; r < 16; ++r) {
        ushort4 sv;
        sv.x = f2b(acc[r][0]); sv.y = f2b(acc[r][1]);
        sv.z = f2b(acc[r][2]); sv.w = f2b(acc[r][3]);
        int m = m0 + r, bb = m >> 11, ss = m & 2047;
        size_t dst = ((size_t)(bb * NB_ + (t >> 6)) * S_ + ss) * 256 + ((t & 63) << 2);
        *(ushort4*)(g_xg + dst) = sv;
    }
}

// ---------- K2: cooperative 4-blocks-per-batch recurrence ----------
// Grid 256 = 64 batches x 4 quarters; block (q= bid>>6, b= bid&63) owns units q*64..q*64+63.
// 512 threads: c2 = t&255 (gate-col: 4*u_local+gate), half = t>>8 (k-half of the dot).
// Weight quarter lives in VGPRs (128 fp32/thread). h exchanged as bf16 pairs via g_hx + g_cnt.
__global__ __launch_bounds__(TPB_, 2) void lstm_coop(const void* __restrict__ Wout,
                                                     const void* __restrict__ bout,
                                                     const void* __restrict__ h0,
                                                     const void* __restrict__ c0,
                                                     void* __restrict__ yv) {
    const int mode = g_mode;
    const int t = threadIdx.x;
    const int bid = blockIdx.x;
    const int q = bid >> 6;
    const int b = bid & 63;
    const int c2 = t & 255;
    const int half = t >> 8;
    const int u_local = c2 >> 2;
    const int gate = c2 & 3;

    __shared__ __align__(16) u32 h2_lds[H_ / 2];   // full h as bf16 pairs
    __shared__ float part[TPB_];
    __shared__ u16 hsl[64];
    __shared__ __align__(16) float wo_lds[H_];

    // --- weights into registers: W[r][half*128 .. +127] as fp32 ---
    float wreg[128];
    {
        int r = gate * H_ + q * 64 + u_local;
        const u32* wp = (const u32*)(g_Whh + (size_t)r * H_ + half * 128);
#pragma unroll
        for (int j = 0; j < 64; ++j) {
            u32 v = wp[j];
            wreg[2 * j]     = b2f((u16)(v & 0xffff));
            wreg[2 * j + 1] = b2f((u16)(v >> 16));
        }
    }

    // --- init state ---
    if (t < 128) {
        u16 lo = f2b(ldin(mode, h0, (size_t)b * H_ + 2 * t));
        u16 hi = f2b(ldin(mode, h0, (size_t)b * H_ + 2 * t + 1));
        h2_lds[t] = (u32)lo | ((u32)hi << 16);
    }
    if (t < H_) wo_lds[t] = ldin(mode, Wout, t);
    float c_reg = 0.0f;
    if (t < 64) c_reg = ldin(mode, c0, (size_t)b * H_ + q * 64 + t);
    const float bo = ldin(mode, bout, 0);
    const u16* xp = g_xg + ((size_t)(b * NB_ + q) * S_) * 256 + c2;
    __syncthreads();

    for (int s = 0; s < S_; ++s) {
        // xg for my column (biases folded in) — issue early, consume after dot
        u16 xvu = 0;
        if (half == 0) xvu = xp[(size_t)s * 256];

        // dot over my k-half with register weights + broadcast h
        float a0 = 0.f, a1 = 0.f, a2 = 0.f, a3 = 0.f;
        {
            const u32* hp = &h2_lds[half << 6];
#pragma unroll
            for (int j4 = 0; j4 < 16; ++j4) {
                uint4 hv = *(const uint4*)(hp + (j4 << 2));
                const float* wr = wreg + (j4 << 3);
                a0 = fmaf(b2f((u16)(hv.x & 0xffff)), wr[0], a0);
                a1 = fmaf(b2f((u16)(hv.x >> 16)),    wr[1], a1);
                a2 = fmaf(b2f((u16)(hv.y & 0xffff)), wr[2], a2);
                a3 = fmaf(b2f((u16)(hv.y >> 16)),    wr[3], a3);
                a0 = fmaf(b2f((u16)(hv.z & 0xffff)), wr[4], a0);
                a1 = fmaf(b2f((u16)(hv.z >> 16)),    wr[5], a1);
                a2 = fmaf(b2f((u16)(hv.w & 0xffff)), wr[6], a2);
                a3 = fmaf(b2f((u16)(hv.w >> 16)),    wr[7], a3);
            }
        }
        float acc = (a0 + a1) + (a2 + a3);
        if (half == 0) acc += b2f(xvu);
        part[t] = acc;
        __syncthreads();                            // (1) partials ready; h2_lds still h_s

        if (t < 64) {
            float gi = clamp30(part[4 * t + 0] + part[256 + 4 * t + 0]);
            float gf = clamp30(part[4 * t + 1] + part[256 + 4 * t + 1]);
            float gg = clamp30(part[4 * t + 2] + part[256 + 4 * t + 2]);
            float go = clamp30(part[4 * t + 3] + part[256 + 4 * t + 3]);
            float ii = sigmoidf_(gi), ff = sigmoidf_(gf);
            float gv = tanhf_(gg), oo = sigmoidf_(go);
            c_reg = fmaf(ff, c_reg, ii * gv);
            hsl[t] = f2b(oo * tanhf_(c_reg));
        } else if (q == 0 && t >= 256 && t < 320 && s > 0) {
            // output head for step s-1 from h2_lds (= hs[s-1]); wave 4, lanes 0..63
            int u4 = t - 256;
            u32 p0 = h2_lds[2 * u4], p1 = h2_lds[2 * u4 + 1];
            float4 w = *(const float4*)(wo_lds + 4 * u4);
            float p = b2f((u16)(p0 & 0xffff)) * w.x + b2f((u16)(p0 >> 16)) * w.y +
                      b2f((u16)(p1 & 0xffff)) * w.z + b2f((u16)(p1 >> 16)) * w.w;
#pragma unroll
            for (int off = 32; off > 0; off >>= 1) p += __shfl_down(p, off, 64);
            if (u4 == 0) {
                float yf = sigmoidf_(clamp30(p + bo));
                if (mode) ((float*)yv)[(size_t)(s - 1) * B_ + b] = yf;
                else      ((u16*)yv)[(size_t)(s - 1) * B_ + b] = f2b(yf);
            }
        }
        __syncthreads();                            // (2) hsl ready; y-reads of h2_lds done

        // publish my h-slice, post, wait for all 4, reload full h
        if (t < 32) {
            u32 v = (u32)hsl[2 * t] | ((u32)hsl[2 * t + 1] << 16);
            __hip_atomic_store(&g_hx[s & 1][b][q * 32 + t], v,
                               __ATOMIC_RELAXED, __HIP_MEMORY_SCOPE_AGENT);
        }
        if (t == 0) {
            __threadfence();                         // slice visible before post
            __hip_atomic_fetch_add(&g_cnt[b], 1, __ATOMIC_RELEASE, __HIP_MEMORY_SCOPE_AGENT);
            while (__hip_atomic_load(&g_cnt[b], __ATOMIC_ACQUIRE, __HIP_MEMORY_SCOPE_AGENT)
                   < NB_ * (s + 1)) { }
        }
        __syncthreads();                            // (3) flag observed by all
        if (t < 128) {
            h2_lds[t] = __hip_atomic_load(&g_hx[s & 1][b][t],
                                          __ATOMIC_RELAXED, __HIP_MEMORY_SCOPE_AGENT);
        }
        __syncthreads();                            // (4) h_{s+1} staged
    }

    // epilogue: y[S-1] from final h (h2_lds = hs[S-1])
    if (q == 0 && t >= 256 && t < 320) {
        int u4 = t - 256;
        u32 p0 = h2_lds[2 * u4], p1 = h2_lds[2 * u4 + 1];
        float4 w = *(const float4*)(wo_lds + 4 * u4);
        float p = b2f((u16)(p0 & 0xffff)) * w.x + b2f((u16)(p0 >> 16)) * w.y +
                  b2f((u16)(p1 & 0xffff)) * w.z + b2f((u16)(p1 >> 16)) * w.w;
#pragma unroll
        for (int off = 32; off > 0; off >>= 1) p += __shfl_down(p, off, 64);
        if (u4 == 0) {
            float yf = sigmoidf_(clamp30(p + bo));
            if (mode) ((float*)yv)[(size_t)(S_ - 1) * B_ + b] = yf;
            else      ((u16*)yv)[(size_t)(S_ - 1) * B_ + b] = f2b(yf);
        }
    }
}

extern "C" void kernel_launch(void* const* d_in, const int* in_sizes, int n_in,
                              void* d_out, int out_size, void* d_ws, size_t ws_size,
                              hipStream_t stream) {
    const void* pw   = d_in[0];   // [B,S,50]
    const void* Wemb = d_in[1];   // [E,50]
    const void* bemb = d_in[2];   // [E]
    const void* Wih  = d_in[3];   // [G,E]
    const void* Whh  = d_in[4];   // [G,H]
    const void* bih  = d_in[5];   // [G]
    const void* bhh  = d_in[6];   // [G]
    const void* Wout = d_in[7];   // [1,H]
    const void* bout = d_in[8];   // [1]
    const void* h0   = d_in[9];   // [B,H]
    const void* c0   = d_in[10];  // [B,H]
    void* y = d_out;              // [S,B]
    (void)d_ws; (void)ws_size;

    sniff_kernel<<<1, 1, 0, stream>>>((const u16*)Wemb);
    transpose_wih<<<(E_ * G_) / 256, 256, 0, stream>>>(Wih);
    prep_whh<<<(G_ * H_) / 256, 256, 0, stream>>>(Whh);
    xg_kernel<<<(B_ * S_) / 16, 256, 0, stream>>>(pw, Wemb, bemb, bih, bhh);

    // cooperative launch for guaranteed co-residency of all 256 blocks
    void* args[] = {(void*)&Wout, (void*)&bout, (void*)&h0, (void*)&c0, (void*)&y};
    hipError_t err = hipLaunchCooperativeKernel((const void*)lstm_coop,
                                                dim3(B_ * NB_), dim3(TPB_),
                                                args, 0, stream);
    if (err != hipSuccess) {
        // fallback: 256 blocks at 1 block/CU on a 256-CU device are co-resident in practice
        lstm_coop<<<B_ * NB_, TPB_, 0, stream>>>(Wout, bout, h0, c0, y);
    }
}

// Round 6
// 8106.930 us; speedup vs baseline: 2.9840x; 2.9840x over previous
//
#include <hip/hip_runtime.h>
#include <hip/hip_bf16.h>

// B=64, S=2048, WIN=50, E=128, H=256, G=4H=1024.
#define B_ 64
#define S_ 2048
#define W_ 50
#define E_ 128
#define H_ 256
#define G_ 1024

typedef unsigned short u16;
typedef unsigned int u32;
typedef _Float16 f16x2 __attribute__((ext_vector_type(2)));

// Module-global scratch (BSS; d_ws untrusted).
__device__ int g_mode;                          // 0 = bf16 buffers, 1 = fp32 buffers
__device__ u16 g_WihT[E_ * G_];                 // [e][4u+q] = Wih[q*H+u][e]  (bf16)
__device__ u32 g_Wpk[128 * G_];                 // [j][c]: f16-pair (Whh[row(c)][2j],[2j+1]), row(c)=(c&3)*256+(c>>2)
__device__ u16 g_xg[(size_t)B_ * S_ * G_];      // [b][s][1024] bf16, biases folded (round-4 validated)

__device__ __forceinline__ float b2f(u16 u) {
    union { u32 i; float f; } v;
    v.i = ((u32)u) << 16;
    return v.f;
}
__device__ __forceinline__ u16 f2b(float f) {
    __hip_bfloat16 h = __float2bfloat16(f);
    return *reinterpret_cast<u16*>(&h);
}
__device__ __forceinline__ float ldin(int mode, const void* p, size_t i) {
    return mode ? ((const float*)p)[i] : b2f(((const u16*)p)[i]);
}
__device__ __forceinline__ float clamp30(float x) {
    return fminf(fmaxf(x, -30.0f), 30.0f);
}
__device__ __forceinline__ float sigmoidf_(float x) { return 1.0f / (1.0f + __expf(-x)); }
__device__ __forceinline__ float tanhf_(float x) {
    float e = __expf(2.0f * x);
    return 1.0f - 2.0f / (e + 1.0f);
}
// packed f16-pair dot: acc += h.lo*w.lo + h.hi*w.hi
__device__ __forceinline__ float dot2f(u32 h, u32 w, float acc) {
#if __has_builtin(__builtin_amdgcn_fdot2)
    union { u32 u; f16x2 v; } a, b;
    a.u = h; b.u = w;
    return __builtin_amdgcn_fdot2(a.v, b.v, acc, false);
#else
    union { u32 u; _Float16 v[2]; } a, b;
    a.u = h; b.u = w;
    return fmaf((float)a.v[1], (float)b.v[1], fmaf((float)a.v[0], (float)b.v[0], acc));
#endif
}

// ---------- K0: dtype sniffer (validated) ----------
__global__ void sniff_kernel(const u16* __restrict__ wemb) {
    int sane = 0;
    for (int i = 0; i < 2048; ++i) {
        int ex = (wemb[i] >> 7) & 0xFF;
        if (ex == 0 || (ex >= 96 && ex <= 143)) ++sane;
    }
    g_mode = (sane >= 1900) ? 0 : 1;
}

// ---------- K0b: Wih gate-interleaved transpose (for xg_kernel) ----------
__global__ __launch_bounds__(256) void transpose_wih(const void* __restrict__ src) {
    const int mode = g_mode;
    int i = blockIdx.x * 256 + threadIdx.x;          // i = e*G + 4u+q
    int e = i >> 10, r = i & 1023, u = r >> 2, q = r & 3;
    g_WihT[i] = f2b(ldin(mode, src, (size_t)((q << 15) + (u << 7) + e)));
}

// ---------- K0c: Whh -> packed f16 pairs, [j][c] layout (coalesced for lstm load) ----------
__global__ __launch_bounds__(256) void prep_wpk(const void* __restrict__ src) {
    const int mode = g_mode;
    int i = blockIdx.x * 256 + threadIdx.x;          // i = j*1024 + c, i < 128*1024
    int j = i >> 10, c = i & 1023;
    int row = ((c & 3) << 8) + (c >> 2);             // gate*256 + unit
    float lo = ldin(mode, src, (size_t)row * H_ + 2 * j);
    float hi = ldin(mode, src, (size_t)row * H_ + 2 * j + 1);
    union { u32 u; f16x2 v; } pk;
    pk.v[0] = (_Float16)lo; pk.v[1] = (_Float16)hi;
    g_Wpk[i] = pk.u;
}

// ---------- K1: fused embedding + input projection (round-4 validated) ----------
__global__ __launch_bounds__(256) void xg_kernel(const void* __restrict__ pw,
                                                 const void* __restrict__ Wemb,
                                                 const void* __restrict__ bemb,
                                                 const void* __restrict__ bih,
                                                 const void* __restrict__ bhh) {
    const int mode = g_mode;
    const int t = threadIdx.x;
    const int m0 = blockIdx.x * 16;
    __shared__ float pw16[16][W_ + 2];
    __shared__ float Wl[E_ * 51];
    __shared__ __align__(16) float erow[16][E_];

    for (int i = t; i < E_ * W_; i += 256) {
        int e = i / W_, w = i - e * W_;
        Wl[e * 51 + w] = ldin(mode, Wemb, i);
    }
    for (int i = t; i < 16 * W_; i += 256) {
        int r = i / W_, w = i - r * W_;
        pw16[r][w] = ldin(mode, pw, (size_t)(m0 + r) * W_ + w);
    }
    __syncthreads();

#pragma unroll
    for (int i = 0; i < 8; ++i) {
        int idx = i * 256 + t;
        int r = idx >> 7, e = idx & 127;
        float a = ldin(mode, bemb, e);
        const float* wr = &Wl[e * 51];
#pragma unroll
        for (int w = 0; w < W_; ++w) a = fmaf(pw16[r][w], wr[w], a);
        erow[r][e] = fmaxf(a, 0.0f);
    }
    __syncthreads();

    const int g0 = 4 * t;
    float acc[16][4];
    {
        float b0 = ldin(mode, bih, t) + ldin(mode, bhh, t);
        float b1 = ldin(mode, bih, H_ + t) + ldin(mode, bhh, H_ + t);
        float b2 = ldin(mode, bih, 2 * H_ + t) + ldin(mode, bhh, 2 * H_ + t);
        float b3 = ldin(mode, bih, 3 * H_ + t) + ldin(mode, bhh, 3 * H_ + t);
#pragma unroll
        for (int r = 0; r < 16; ++r) { acc[r][0] = b0; acc[r][1] = b1; acc[r][2] = b2; acc[r][3] = b3; }
    }
    for (int e = 0; e < E_; e += 4) {
        ushort4 w0 = *(const ushort4*)(g_WihT + (size_t)(e + 0) * G_ + g0);
        ushort4 w1 = *(const ushort4*)(g_WihT + (size_t)(e + 1) * G_ + g0);
        ushort4 w2 = *(const ushort4*)(g_WihT + (size_t)(e + 2) * G_ + g0);
        ushort4 w3 = *(const ushort4*)(g_WihT + (size_t)(e + 3) * G_ + g0);
        float f00 = b2f(w0.x), f01 = b2f(w0.y), f02 = b2f(w0.z), f03 = b2f(w0.w);
        float f10 = b2f(w1.x), f11 = b2f(w1.y), f12 = b2f(w1.z), f13 = b2f(w1.w);
        float f20 = b2f(w2.x), f21 = b2f(w2.y), f22 = b2f(w2.z), f23 = b2f(w2.w);
        float f30 = b2f(w3.x), f31 = b2f(w3.y), f32 = b2f(w3.z), f33 = b2f(w3.w);
#pragma unroll
        for (int r = 0; r < 16; ++r) {
            float4 ev = *(const float4*)&erow[r][e];
            acc[r][0] = fmaf(ev.x, f00, acc[r][0]); acc[r][1] = fmaf(ev.x, f01, acc[r][1]);
            acc[r][2] = fmaf(ev.x, f02, acc[r][2]); acc[r][3] = fmaf(ev.x, f03, acc[r][3]);
            acc[r][0] = fmaf(ev.y, f10, acc[r][0]); acc[r][1] = fmaf(ev.y, f11, acc[r][1]);
            acc[r][2] = fmaf(ev.y, f12, acc[r][2]); acc[r][3] = fmaf(ev.y, f13, acc[r][3]);
            acc[r][0] = fmaf(ev.z, f20, acc[r][0]); acc[r][1] = fmaf(ev.z, f21, acc[r][1]);
            acc[r][2] = fmaf(ev.z, f22, acc[r][2]); acc[r][3] = fmaf(ev.z, f23, acc[r][3]);
            acc[r][0] = fmaf(ev.w, f30, acc[r][0]); acc[r][1] = fmaf(ev.w, f31, acc[r][1]);
            acc[r][2] = fmaf(ev.w, f32, acc[r][2]); acc[r][3] = fmaf(ev.w, f33, acc[r][3]);
        }
    }
#pragma unroll
    for (int r = 0; r < 16; ++r) {
        ushort4 sv;
        sv.x = f2b(acc[r][0]); sv.y = f2b(acc[r][1]);
        sv.z = f2b(acc[r][2]); sv.w = f2b(acc[r][3]);
        *(ushort4*)(g_xg + (size_t)(m0 + r) * G_ + g0) = sv;
    }
}

// ---------- K2: recurrence, one block per batch, W_hh register-resident ----------
// 64 blocks x 1024 threads. Thread t owns gate-column c = t (= 4*unit + gate),
// holds all K=256 weights as 128 packed f16-pair u32s. h broadcast from LDS (f16).
__global__ __launch_bounds__(1024) void lstm_reg(const void* __restrict__ Wout,
                                                 const void* __restrict__ bout,
                                                 const void* __restrict__ h0,
                                                 const void* __restrict__ c0,
                                                 void* __restrict__ yv) {
    const int mode = g_mode;
    const int t = threadIdx.x;
    const int b = blockIdx.x;

    __shared__ __align__(16) u16 h16[H_];        // h as f16
    __shared__ __align__(16) float gl[G_];       // gate pre-activations
    __shared__ float red[4];

    // --- weights into registers: 128 u32, coalesced ([j][c] layout) ---
    u32 wpk[128];
#pragma unroll
    for (int j = 0; j < 128; ++j) wpk[j] = g_Wpk[(size_t)j * G_ + t];

    // --- init state ---
    float c_reg = 0.0f, wo = 0.0f;
    if (t < H_) {
        c_reg = ldin(mode, c0, (size_t)b * H_ + t);
        union { u16 u; _Float16 v; } hh;
        hh.v = (_Float16)ldin(mode, h0, (size_t)b * H_ + t);
        h16[t] = hh.u;
        wo = ldin(mode, Wout, t);
    }
    const float bo = ldin(mode, bout, 0);
    const u16* xp = g_xg + (size_t)b * S_ * G_ + t;
    __syncthreads();

    for (int s = 0; s < S_; ++s) {
        u16 xv = xp[(size_t)s * G_];             // bf16; issued early, used after dots

        float a0 = 0.f, a1 = 0.f, a2 = 0.f, a3 = 0.f;
        const u32* hp = (const u32*)h16;         // 128 packed f16 pairs, wave-uniform reads
#pragma unroll
        for (int j4 = 0; j4 < 32; ++j4) {
            uint4 hv = *(const uint4*)(hp + (j4 << 2));
            a0 = dot2f(hv.x, wpk[4 * j4 + 0], a0);
            a1 = dot2f(hv.y, wpk[4 * j4 + 1], a1);
            a2 = dot2f(hv.z, wpk[4 * j4 + 2], a2);
            a3 = dot2f(hv.w, wpk[4 * j4 + 3], a3);
        }
        gl[t] = (a0 + a1) + (a2 + a3) + b2f(xv);
        __syncthreads();                          // (1) gates ready; h16 reads done

        if (t < H_) {
            float4 g4 = *(const float4*)(gl + 4 * t);
            float ii = sigmoidf_(clamp30(g4.x));
            float ff = sigmoidf_(clamp30(g4.y));
            float gv = tanhf_(clamp30(g4.z));
            float oo = sigmoidf_(clamp30(g4.w));
            c_reg = fmaf(ff, c_reg, ii * gv);
            float h = oo * tanhf_(c_reg);
            union { u16 u; _Float16 v; } hh;
            hh.v = (_Float16)h;
            h16[t] = hh.u;
            float p = h * wo;
#pragma unroll
            for (int off = 32; off > 0; off >>= 1) p += __shfl_down(p, off, 64);
            if ((t & 63) == 0) red[t >> 6] = p;
        }
        __syncthreads();                          // (2) h16 + red ready

        if (t == 0) {
            float yf = sigmoidf_(clamp30(red[0] + red[1] + red[2] + red[3] + bo));
            if (mode) ((float*)yv)[(size_t)s * B_ + b] = yf;
            else      ((u16*)yv)[(size_t)s * B_ + b] = f2b(yf);
        }
    }
}

extern "C" void kernel_launch(void* const* d_in, const int* in_sizes, int n_in,
                              void* d_out, int out_size, void* d_ws, size_t ws_size,
                              hipStream_t stream) {
    const void* pw   = d_in[0];   // [B,S,50]
    const void* Wemb = d_in[1];   // [E,50]
    const void* bemb = d_in[2];   // [E]
    const void* Wih  = d_in[3];   // [G,E]
    const void* Whh  = d_in[4];   // [G,H]
    const void* bih  = d_in[5];   // [G]
    const void* bhh  = d_in[6];   // [G]
    const void* Wout = d_in[7];   // [1,H]
    const void* bout = d_in[8];   // [1]
    const void* h0   = d_in[9];   // [B,H]
    const void* c0   = d_in[10];  // [B,H]
    void* y = d_out;              // [S,B]
    (void)d_ws; (void)ws_size;

    sniff_kernel<<<1, 1, 0, stream>>>((const u16*)Wemb);
    transpose_wih<<<(E_ * G_) / 256, 256, 0, stream>>>(Wih);
    prep_wpk<<<(128 * G_) / 256, 256, 0, stream>>>(Whh);
    xg_kernel<<<(B_ * S_) / 16, 256, 0, stream>>>(pw, Wemb, bemb, bih, bhh);
    lstm_reg<<<B_, 1024, 0, stream>>>(Wout, bout, h0, c0, y);
}

// Round 7
// 3475.093 us; speedup vs baseline: 6.9613x; 2.3329x over previous
//
#include <hip/hip_runtime.h>
#include <hip/hip_bf16.h>

// B=64, S=2048, WIN=50, E=128, H=256, G=4H=1024.
#define B_ 64
#define S_ 2048
#define W_ 50
#define E_ 128
#define H_ 256
#define G_ 1024

typedef unsigned short u16;
typedef unsigned int u32;

// Module-global scratch (BSS; d_ws untrusted).
__device__ int g_mode;                          // 0 = bf16 buffers, 1 = fp32 buffers
__device__ u16 g_WihT[E_ * G_];                 // [e][4u+q] = Wih[q*H+u][e]  (bf16)
__device__ u32 g_Wi8[64 * G_];                  // [j][c]: 4×i8 = Whh[row(c)][4j..4j+3], row(c)=(c&3)*256+(c>>2)
__device__ float g_wscale[G_];                  // per-column dequant: max|W[:,c]|/(127*127)
__device__ u16 g_xg[(size_t)B_ * S_ * G_];      // [b][s][1024] bf16, biases folded (validated)

__device__ __forceinline__ float b2f(u16 u) {
    union { u32 i; float f; } v;
    v.i = ((u32)u) << 16;
    return v.f;
}
__device__ __forceinline__ u16 f2b(float f) {
    __hip_bfloat16 h = __float2bfloat16(f);
    return *reinterpret_cast<u16*>(&h);
}
__device__ __forceinline__ float ldin(int mode, const void* p, size_t i) {
    return mode ? ((const float*)p)[i] : b2f(((const u16*)p)[i]);
}
__device__ __forceinline__ float clamp30(float x) {
    return fminf(fmaxf(x, -30.0f), 30.0f);
}
__device__ __forceinline__ float sigmoidf_(float x) { return 1.0f / (1.0f + __expf(-x)); }
__device__ __forceinline__ float tanhf_(float x) {
    float e = __expf(2.0f * x);
    return 1.0f - 2.0f / (e + 1.0f);
}
// int8x4 dot: acc += sum_i (i8)a[i] * (i8)b[i]
__device__ __forceinline__ int dot4i8(u32 a, u32 b, int acc) {
#if __has_builtin(__builtin_amdgcn_sdot4)
    return __builtin_amdgcn_sdot4(a, b, acc, false);
#else
    acc += (int)(signed char)(a)       * (int)(signed char)(b);
    acc += (int)(signed char)(a >> 8)  * (int)(signed char)(b >> 8);
    acc += (int)(signed char)(a >> 16) * (int)(signed char)(b >> 16);
    acc += (int)(signed char)(a >> 24) * (int)(signed char)(b >> 24);
    return acc;
#endif
}

// ---------- K0: dtype sniffer (validated) ----------
__global__ void sniff_kernel(const u16* __restrict__ wemb) {
    int sane = 0;
    for (int i = 0; i < 2048; ++i) {
        int ex = (wemb[i] >> 7) & 0xFF;
        if (ex == 0 || (ex >= 96 && ex <= 143)) ++sane;
    }
    g_mode = (sane >= 1900) ? 0 : 1;
}

// ---------- K0b: Wih gate-interleaved transpose (for xg_kernel) ----------
__global__ __launch_bounds__(256) void transpose_wih(const void* __restrict__ src) {
    const int mode = g_mode;
    int i = blockIdx.x * 256 + threadIdx.x;          // i = e*G + 4u+q
    int e = i >> 10, r = i & 1023, u = r >> 2, q = r & 3;
    g_WihT[i] = f2b(ldin(mode, src, (size_t)((q << 15) + (u << 7) + e)));
}

// ---------- K0c: Whh -> int8 per-column-scaled, [j][c] layout ----------
// Column c (= 4*unit+gate) maps to Whh row = gate*256 + unit (validated rounds 4/6).
__global__ __launch_bounds__(256) void prep_wi8(const void* __restrict__ src) {
    const int mode = g_mode;
    int c = blockIdx.x * 256 + threadIdx.x;          // 0..1023
    int row = ((c & 3) << 8) + (c >> 2);
    const size_t base = (size_t)row * H_;
    float m = 0.0f;
    for (int k = 0; k < H_; ++k) m = fmaxf(m, fabsf(ldin(mode, src, base + k)));
    float inv = (m > 0.0f) ? 127.0f / m : 0.0f;
    g_wscale[c] = m / (127.0f * 127.0f);             // w-scale * h-scale(1/127)
    for (int j = 0; j < 64; ++j) {
        u32 pk = 0;
#pragma unroll
        for (int i = 0; i < 4; ++i) {
            int q = (int)rintf(ldin(mode, src, base + 4 * j + i) * inv);
            q = max(-127, min(127, q));
            pk |= ((u32)(q & 0xff)) << (8 * i);
        }
        g_Wi8[(size_t)j * G_ + c] = pk;
    }
}

// ---------- K1: fused embedding + input projection (validated round 4) ----------
__global__ __launch_bounds__(256) void xg_kernel(const void* __restrict__ pw,
                                                 const void* __restrict__ Wemb,
                                                 const void* __restrict__ bemb,
                                                 const void* __restrict__ bih,
                                                 const void* __restrict__ bhh) {
    const int mode = g_mode;
    const int t = threadIdx.x;
    const int m0 = blockIdx.x * 16;
    __shared__ float pw16[16][W_ + 2];
    __shared__ float Wl[E_ * 51];
    __shared__ __align__(16) float erow[16][E_];

    for (int i = t; i < E_ * W_; i += 256) {
        int e = i / W_, w = i - e * W_;
        Wl[e * 51 + w] = ldin(mode, Wemb, i);
    }
    for (int i = t; i < 16 * W_; i += 256) {
        int r = i / W_, w = i - r * W_;
        pw16[r][w] = ldin(mode, pw, (size_t)(m0 + r) * W_ + w);
    }
    __syncthreads();

#pragma unroll
    for (int i = 0; i < 8; ++i) {
        int idx = i * 256 + t;
        int r = idx >> 7, e = idx & 127;
        float a = ldin(mode, bemb, e);
        const float* wr = &Wl[e * 51];
#pragma unroll
        for (int w = 0; w < W_; ++w) a = fmaf(pw16[r][w], wr[w], a);
        erow[r][e] = fmaxf(a, 0.0f);
    }
    __syncthreads();

    const int g0 = 4 * t;
    float acc[16][4];
    {
        float b0 = ldin(mode, bih, t) + ldin(mode, bhh, t);
        float b1 = ldin(mode, bih, H_ + t) + ldin(mode, bhh, H_ + t);
        float b2 = ldin(mode, bih, 2 * H_ + t) + ldin(mode, bhh, 2 * H_ + t);
        float b3 = ldin(mode, bih, 3 * H_ + t) + ldin(mode, bhh, 3 * H_ + t);
#pragma unroll
        for (int r = 0; r < 16; ++r) { acc[r][0] = b0; acc[r][1] = b1; acc[r][2] = b2; acc[r][3] = b3; }
    }
    for (int e = 0; e < E_; e += 4) {
        ushort4 w0 = *(const ushort4*)(g_WihT + (size_t)(e + 0) * G_ + g0);
        ushort4 w1 = *(const ushort4*)(g_WihT + (size_t)(e + 1) * G_ + g0);
        ushort4 w2 = *(const ushort4*)(g_WihT + (size_t)(e + 2) * G_ + g0);
        ushort4 w3 = *(const ushort4*)(g_WihT + (size_t)(e + 3) * G_ + g0);
        float f00 = b2f(w0.x), f01 = b2f(w0.y), f02 = b2f(w0.z), f03 = b2f(w0.w);
        float f10 = b2f(w1.x), f11 = b2f(w1.y), f12 = b2f(w1.z), f13 = b2f(w1.w);
        float f20 = b2f(w2.x), f21 = b2f(w2.y), f22 = b2f(w2.z), f23 = b2f(w2.w);
        float f30 = b2f(w3.x), f31 = b2f(w3.y), f32 = b2f(w3.z), f33 = b2f(w3.w);
#pragma unroll
        for (int r = 0; r < 16; ++r) {
            float4 ev = *(const float4*)&erow[r][e];
            acc[r][0] = fmaf(ev.x, f00, acc[r][0]); acc[r][1] = fmaf(ev.x, f01, acc[r][1]);
            acc[r][2] = fmaf(ev.x, f02, acc[r][2]); acc[r][3] = fmaf(ev.x, f03, acc[r][3]);
            acc[r][0] = fmaf(ev.y, f10, acc[r][0]); acc[r][1] = fmaf(ev.y, f11, acc[r][1]);
            acc[r][2] = fmaf(ev.y, f12, acc[r][2]); acc[r][3] = fmaf(ev.y, f13, acc[r][3]);
            acc[r][0] = fmaf(ev.z, f20, acc[r][0]); acc[r][1] = fmaf(ev.z, f21, acc[r][1]);
            acc[r][2] = fmaf(ev.z, f22, acc[r][2]); acc[r][3] = fmaf(ev.z, f23, acc[r][3]);
            acc[r][0] = fmaf(ev.w, f30, acc[r][0]); acc[r][1] = fmaf(ev.w, f31, acc[r][1]);
            acc[r][2] = fmaf(ev.w, f32, acc[r][2]); acc[r][3] = fmaf(ev.w, f33, acc[r][3]);
        }
    }
#pragma unroll
    for (int r = 0; r < 16; ++r) {
        ushort4 sv;
        sv.x = f2b(acc[r][0]); sv.y = f2b(acc[r][1]);
        sv.z = f2b(acc[r][2]); sv.w = f2b(acc[r][3]);
        *(ushort4*)(g_xg + (size_t)(m0 + r) * G_ + g0) = sv;
    }
}

// ---------- K2: recurrence, one block per batch, W_hh int8-register-resident ----------
// 64 blocks x 1024 threads; thread t owns gate-column t (4*unit+gate), all K=256 as
// 64 u32 int8-quads. h exchanged as packed i8 (scale 1/127) through 256 B of LDS.
// __launch_bounds__(1024, 4): force 1 block/CU -> 128-VGPR cap so wreg[64] stays resident.
__global__ __launch_bounds__(1024, 4) void lstm_i8(const void* __restrict__ Wout,
                                                   const void* __restrict__ bout,
                                                   const void* __restrict__ h0,
                                                   const void* __restrict__ c0,
                                                   void* __restrict__ yv) {
    const int mode = g_mode;
    const int t = threadIdx.x;
    const int b = blockIdx.x;

    __shared__ __align__(16) u32 h8[H_ / 4];     // h as i8, 64 words
    __shared__ __align__(16) float gl[G_];       // gate pre-activations
    __shared__ float red[4];

    // --- weights into registers: 64 u32, coalesced ([j][c] layout) ---
    u32 wreg[64];
#pragma unroll
    for (int j = 0; j < 64; ++j) wreg[j] = g_Wi8[(size_t)j * G_ + t];
    const float wsc = g_wscale[t];

    // --- init state ---
    float c_reg = 0.0f, wo = 0.0f;
    if (t < H_) {
        c_reg = ldin(mode, c0, (size_t)b * H_ + t);
        wo = ldin(mode, Wout, t);
    }
    if (t < H_ / 4) {
        u32 pk = 0;
#pragma unroll
        for (int i = 0; i < 4; ++i) {
            float h = ldin(mode, h0, (size_t)b * H_ + 4 * t + i);
            int q = (int)rintf(fminf(fmaxf(h, -1.0f), 1.0f) * 127.0f);
            pk |= ((u32)(q & 0xff)) << (8 * i);
        }
        h8[t] = pk;
    }
    const float bo = ldin(mode, bout, 0);
    const u16* xp = g_xg + (size_t)b * S_ * G_ + t;
    u16 xv = xp[0];
    __syncthreads();

    for (int s = 0; s < S_; ++s) {
        // dot over K=256: 16 broadcast uint4 LDS reads + 64 int8 dot4s
        int acc = 0;
        const uint4* hp = (const uint4*)h8;
#pragma unroll
        for (int j4 = 0; j4 < 16; ++j4) {
            uint4 hv = hp[j4];
            acc = dot4i8(hv.x, wreg[4 * j4 + 0], acc);
            acc = dot4i8(hv.y, wreg[4 * j4 + 1], acc);
            acc = dot4i8(hv.z, wreg[4 * j4 + 2], acc);
            acc = dot4i8(hv.w, wreg[4 * j4 + 3], acc);
        }
        gl[t] = (float)acc * wsc + b2f(xv);
        if (s + 1 < S_) xv = xp[(size_t)(s + 1) * G_];   // prefetch next step's xg
        __syncthreads();                          // (1) gates ready; h8 reads done

        if (t < H_) {
            float4 g4 = *(const float4*)(gl + 4 * t);
            float ii = sigmoidf_(clamp30(g4.x));
            float ff = sigmoidf_(clamp30(g4.y));
            float gv = tanhf_(clamp30(g4.z));
            float oo = sigmoidf_(clamp30(g4.w));
            c_reg = fmaf(ff, c_reg, ii * gv);
            float h = oo * tanhf_(c_reg);
            // quantize + pack 4 lanes' h into one u32 (unit t -> byte t&3 of word t>>2)
            int q = (int)rintf(fminf(fmaxf(h, -1.0f), 1.0f) * 127.0f) & 0xff;
            int q1 = __shfl_down(q, 1, 64);
            int q2 = __shfl_down(q, 2, 64);
            int q3 = __shfl_down(q, 3, 64);
            if ((t & 3) == 0)
                h8[t >> 2] = (u32)q | ((u32)q1 << 8) | ((u32)q2 << 16) | ((u32)q3 << 24);
            // output head partial
            float p = h * wo;
#pragma unroll
            for (int off = 32; off > 0; off >>= 1) p += __shfl_down(p, off, 64);
            if ((t & 63) == 0) red[t >> 6] = p;
        }
        __syncthreads();                          // (2) h8 + red ready

        if (t == 0) {
            float yf = sigmoidf_(clamp30(red[0] + red[1] + red[2] + red[3] + bo));
            if (mode) ((float*)yv)[(size_t)s * B_ + b] = yf;
            else      ((u16*)yv)[(size_t)s * B_ + b] = f2b(yf);
        }
    }
}

extern "C" void kernel_launch(void* const* d_in, const int* in_sizes, int n_in,
                              void* d_out, int out_size, void* d_ws, size_t ws_size,
                              hipStream_t stream) {
    const void* pw   = d_in[0];   // [B,S,50]
    const void* Wemb = d_in[1];   // [E,50]
    const void* bemb = d_in[2];   // [E]
    const void* Wih  = d_in[3];   // [G,E]
    const void* Whh  = d_in[4];   // [G,H]
    const void* bih  = d_in[5];   // [G]
    const void* bhh  = d_in[6];   // [G]
    const void* Wout = d_in[7];   // [1,H]
    const void* bout = d_in[8];   // [1]
    const void* h0   = d_in[9];   // [B,H]
    const void* c0   = d_in[10];  // [B,H]
    void* y = d_out;              // [S,B]
    (void)d_ws; (void)ws_size;

    sniff_kernel<<<1, 1, 0, stream>>>((const u16*)Wemb);
    transpose_wih<<<(E_ * G_) / 256, 256, 0, stream>>>(Wih);
    prep_wi8<<<G_ / 256, 256, 0, stream>>>(Whh);
    xg_kernel<<<(B_ * S_) / 16, 256, 0, stream>>>(pw, Wemb, bemb, bih, bhh);
    lstm_i8<<<B_, 1024, 0, stream>>>(Wout, bout, h0, c0, y);
}

// Round 8
// 3289.808 us; speedup vs baseline: 7.3534x; 1.0563x over previous
//
#include <hip/hip_runtime.h>
#include <hip/hip_bf16.h>

// B=64, S=2048, WIN=50, E=128, H=256, G=4H=1024.
#define B_ 64
#define S_ 2048
#define W_ 50
#define E_ 128
#define H_ 256
#define G_ 1024

typedef unsigned short u16;
typedef unsigned int u32;

// Module-global scratch (BSS; d_ws untrusted).
__device__ int g_mode;                          // 0 = bf16 buffers, 1 = fp32 buffers
__device__ u16 g_WihT[E_ * G_];                 // [e][4u+q] = Wih[q*H+u][e]  (bf16)
__device__ u32 g_Wi8[G_ * 64];                  // [c][j]: 4×i8 = Whh[row(c)][4j..4j+3], row(c)=(c&3)*256+(c>>2)
__device__ float g_wscale[G_];                  // per-column dequant: max|W[:,c]| * (1/127) * (1/127)
__device__ u16 g_xg[(size_t)B_ * S_ * G_];      // [b][s][1024] bf16, biases folded (validated)

__device__ __forceinline__ float b2f(u16 u) {
    union { u32 i; float f; } v;
    v.i = ((u32)u) << 16;
    return v.f;
}
__device__ __forceinline__ u16 f2b(float f) {
    __hip_bfloat16 h = __float2bfloat16(f);
    return *reinterpret_cast<u16*>(&h);
}
__device__ __forceinline__ float ldin(int mode, const void* p, size_t i) {
    return mode ? ((const float*)p)[i] : b2f(((const u16*)p)[i]);
}
__device__ __forceinline__ float clamp30(float x) {
    return fminf(fmaxf(x, -30.0f), 30.0f);
}
__device__ __forceinline__ float sigmoidf_(float x) { return 1.0f / (1.0f + __expf(-x)); }
__device__ __forceinline__ float tanhf_(float x) {
    float e = __expf(2.0f * x);
    return 1.0f - 2.0f / (e + 1.0f);
}
// int8x4 dot: acc += sum_i (i8)a[i] * (i8)b[i]
__device__ __forceinline__ int dot4i8(u32 a, u32 b, int acc) {
#if __has_builtin(__builtin_amdgcn_sdot4)
    return __builtin_amdgcn_sdot4(a, b, acc, false);
#else
    acc += (int)(signed char)(a)       * (int)(signed char)(b);
    acc += (int)(signed char)(a >> 8)  * (int)(signed char)(b >> 8);
    acc += (int)(signed char)(a >> 16) * (int)(signed char)(b >> 16);
    acc += (int)(signed char)(a >> 24) * (int)(signed char)(b >> 24);
    return acc;
#endif
}

// ---------- K0: dtype sniffer (validated) ----------
__global__ void sniff_kernel(const u16* __restrict__ wemb) {
    int sane = 0;
    for (int i = 0; i < 2048; ++i) {
        int ex = (wemb[i] >> 7) & 0xFF;
        if (ex == 0 || (ex >= 96 && ex <= 143)) ++sane;
    }
    g_mode = (sane >= 1900) ? 0 : 1;
}

// ---------- K0b: Wih gate-interleaved transpose (for xg_kernel) ----------
__global__ __launch_bounds__(256) void transpose_wih(const void* __restrict__ src) {
    const int mode = g_mode;
    int i = blockIdx.x * 256 + threadIdx.x;          // i = e*G + 4u+q
    int e = i >> 10, r = i & 1023, u = r >> 2, q = r & 3;
    g_WihT[i] = f2b(ldin(mode, src, (size_t)((q << 15) + (u << 7) + e)));
}

// ---------- K0c: Whh -> int8 per-column-scaled, [c][j] layout ----------
// Column c (= 4*unit+gate) maps to Whh row = gate*256 + unit (validated).
__global__ __launch_bounds__(256) void prep_wi8(const void* __restrict__ src) {
    const int mode = g_mode;
    int c = blockIdx.x * 256 + threadIdx.x;          // 0..1023
    int row = ((c & 3) << 8) + (c >> 2);
    const size_t base = (size_t)row * H_;
    float m = 0.0f;
    for (int k = 0; k < H_; ++k) m = fmaxf(m, fabsf(ldin(mode, src, base + k)));
    float inv = (m > 0.0f) ? 127.0f / m : 0.0f;
    g_wscale[c] = m / (127.0f * 127.0f);             // w-scale * h-scale(1/127)
    for (int j = 0; j < 64; ++j) {
        u32 pk = 0;
#pragma unroll
        for (int i = 0; i < 4; ++i) {
            int q = (int)rintf(ldin(mode, src, base + 4 * j + i) * inv);
            q = max(-127, min(127, q));
            pk |= ((u32)(q & 0xff)) << (8 * i);
        }
        g_Wi8[(size_t)c * 64 + j] = pk;              // contiguous per column
    }
}

// ---------- K1: fused embedding + input projection (validated round 4) ----------
__global__ __launch_bounds__(256) void xg_kernel(const void* __restrict__ pw,
                                                 const void* __restrict__ Wemb,
                                                 const void* __restrict__ bemb,
                                                 const void* __restrict__ bih,
                                                 const void* __restrict__ bhh) {
    const int mode = g_mode;
    const int t = threadIdx.x;
    const int m0 = blockIdx.x * 16;
    __shared__ float pw16[16][W_ + 2];
    __shared__ float Wl[E_ * 51];
    __shared__ __align__(16) float erow[16][E_];

    for (int i = t; i < E_ * W_; i += 256) {
        int e = i / W_, w = i - e * W_;
        Wl[e * 51 + w] = ldin(mode, Wemb, i);
    }
    for (int i = t; i < 16 * W_; i += 256) {
        int r = i / W_, w = i - r * W_;
        pw16[r][w] = ldin(mode, pw, (size_t)(m0 + r) * W_ + w);
    }
    __syncthreads();

#pragma unroll
    for (int i = 0; i < 8; ++i) {
        int idx = i * 256 + t;
        int r = idx >> 7, e = idx & 127;
        float a = ldin(mode, bemb, e);
        const float* wr = &Wl[e * 51];
#pragma unroll
        for (int w = 0; w < W_; ++w) a = fmaf(pw16[r][w], wr[w], a);
        erow[r][e] = fmaxf(a, 0.0f);
    }
    __syncthreads();

    const int g0 = 4 * t;
    float acc[16][4];
    {
        float b0 = ldin(mode, bih, t) + ldin(mode, bhh, t);
        float b1 = ldin(mode, bih, H_ + t) + ldin(mode, bhh, H_ + t);
        float b2 = ldin(mode, bih, 2 * H_ + t) + ldin(mode, bhh, 2 * H_ + t);
        float b3 = ldin(mode, bih, 3 * H_ + t) + ldin(mode, bhh, 3 * H_ + t);
#pragma unroll
        for (int r = 0; r < 16; ++r) { acc[r][0] = b0; acc[r][1] = b1; acc[r][2] = b2; acc[r][3] = b3; }
    }
    for (int e = 0; e < E_; e += 4) {
        ushort4 w0 = *(const ushort4*)(g_WihT + (size_t)(e + 0) * G_ + g0);
        ushort4 w1 = *(const ushort4*)(g_WihT + (size_t)(e + 1) * G_ + g0);
        ushort4 w2 = *(const ushort4*)(g_WihT + (size_t)(e + 2) * G_ + g0);
        ushort4 w3 = *(const ushort4*)(g_WihT + (size_t)(e + 3) * G_ + g0);
        float f00 = b2f(w0.x), f01 = b2f(w0.y), f02 = b2f(w0.z), f03 = b2f(w0.w);
        float f10 = b2f(w1.x), f11 = b2f(w1.y), f12 = b2f(w1.z), f13 = b2f(w1.w);
        float f20 = b2f(w2.x), f21 = b2f(w2.y), f22 = b2f(w2.z), f23 = b2f(w2.w);
        float f30 = b2f(w3.x), f31 = b2f(w3.y), f32 = b2f(w3.z), f33 = b2f(w3.w);
#pragma unroll
        for (int r = 0; r < 16; ++r) {
            float4 ev = *(const float4*)&erow[r][e];
            acc[r][0] = fmaf(ev.x, f00, acc[r][0]); acc[r][1] = fmaf(ev.x, f01, acc[r][1]);
            acc[r][2] = fmaf(ev.x, f02, acc[r][2]); acc[r][3] = fmaf(ev.x, f03, acc[r][3]);
            acc[r][0] = fmaf(ev.y, f10, acc[r][0]); acc[r][1] = fmaf(ev.y, f11, acc[r][1]);
            acc[r][2] = fmaf(ev.y, f12, acc[r][2]); acc[r][3] = fmaf(ev.y, f13, acc[r][3]);
            acc[r][0] = fmaf(ev.z, f20, acc[r][0]); acc[r][1] = fmaf(ev.z, f21, acc[r][1]);
            acc[r][2] = fmaf(ev.z, f22, acc[r][2]); acc[r][3] = fmaf(ev.z, f23, acc[r][3]);
            acc[r][0] = fmaf(ev.w, f30, acc[r][0]); acc[r][1] = fmaf(ev.w, f31, acc[r][1]);
            acc[r][2] = fmaf(ev.w, f32, acc[r][2]); acc[r][3] = fmaf(ev.w, f33, acc[r][3]);
        }
    }
#pragma unroll
    for (int r = 0; r < 16; ++r) {
        ushort4 sv;
        sv.x = f2b(acc[r][0]); sv.y = f2b(acc[r][1]);
        sv.z = f2b(acc[r][2]); sv.w = f2b(acc[r][3]);
        *(ushort4*)(g_xg + (size_t)(m0 + r) * G_ + g0) = sv;
    }
}

// ---------- K2: recurrence, one block per batch, W_hh in NAMED uint4 registers ----------
// 64 blocks x 1024 threads; thread t owns gate-column t (4*unit+gate), all K=256 as
// 16 named uint4 (64 u32 int8-quads) — named scalars dodge SROA's alloca limits.
// h exchanged as packed i8 (scale 1/127) through 256 B of LDS.
__global__ __launch_bounds__(1024, 4) void lstm_i8(const void* __restrict__ Wout,
                                                   const void* __restrict__ bout,
                                                   const void* __restrict__ h0,
                                                   const void* __restrict__ c0,
                                                   void* __restrict__ yv) {
    const int mode = g_mode;
    const int t = threadIdx.x;
    const int b = blockIdx.x;

    __shared__ __align__(16) u32 h8[H_ / 4];     // h as i8, 64 words
    __shared__ __align__(16) float gl[G_];       // gate pre-activations
    __shared__ float red[4];

    // --- weights into 16 named uint4 (contiguous [c][64] layout) ---
    const uint4* wp = (const uint4*)(g_Wi8 + (size_t)t * 64);
    uint4 W0 = wp[0],  W1 = wp[1],  W2 = wp[2],  W3 = wp[3];
    uint4 W4 = wp[4],  W5 = wp[5],  W6 = wp[6],  W7 = wp[7];
    uint4 W8 = wp[8],  W9 = wp[9],  W10 = wp[10], W11 = wp[11];
    uint4 W12 = wp[12], W13 = wp[13], W14 = wp[14], W15 = wp[15];
    const float wsc = g_wscale[t];

    // --- init state ---
    float c_reg = 0.0f, wo = 0.0f;
    if (t < H_) {
        c_reg = ldin(mode, c0, (size_t)b * H_ + t);
        wo = ldin(mode, Wout, t);
    }
    if (t < H_ / 4) {
        u32 pk = 0;
#pragma unroll
        for (int i = 0; i < 4; ++i) {
            float h = ldin(mode, h0, (size_t)b * H_ + 4 * t + i);
            int q = (int)rintf(fminf(fmaxf(h, -1.0f), 1.0f) * 127.0f);
            pk |= ((u32)(q & 0xff)) << (8 * i);
        }
        h8[t] = pk;
    }
    const float bo = ldin(mode, bout, 0);
    const u16* xp = g_xg + (size_t)b * S_ * G_ + t;
    u16 xv = xp[0];
    __syncthreads();

    for (int s = 0; s < S_; ++s) {
        // dot over K=256: 16 broadcast uint4 LDS reads + 64 int8 dot4s
        int acc = 0;
        const uint4* hp = (const uint4*)h8;
#define DOT16(WV, IDX)                                   \
        {                                                \
            uint4 hv = hp[IDX];                          \
            acc = dot4i8(hv.x, WV.x, acc);               \
            acc = dot4i8(hv.y, WV.y, acc);               \
            acc = dot4i8(hv.z, WV.z, acc);               \
            acc = dot4i8(hv.w, WV.w, acc);               \
        }
        DOT16(W0, 0)  DOT16(W1, 1)  DOT16(W2, 2)  DOT16(W3, 3)
        DOT16(W4, 4)  DOT16(W5, 5)  DOT16(W6, 6)  DOT16(W7, 7)
        DOT16(W8, 8)  DOT16(W9, 9)  DOT16(W10, 10) DOT16(W11, 11)
        DOT16(W12, 12) DOT16(W13, 13) DOT16(W14, 14) DOT16(W15, 15)
#undef DOT16
        gl[t] = (float)acc * wsc + b2f(xv);
        if (s + 1 < S_) xv = xp[(size_t)(s + 1) * G_];   // prefetch next step's xg
        __syncthreads();                          // (1) gates ready; h8 reads done

        if (t < H_) {
            float4 g4 = *(const float4*)(gl + 4 * t);
            float ii = sigmoidf_(clamp30(g4.x));
            float ff = sigmoidf_(clamp30(g4.y));
            float gv = tanhf_(clamp30(g4.z));
            float oo = sigmoidf_(clamp30(g4.w));
            c_reg = fmaf(ff, c_reg, ii * gv);
            float h = oo * tanhf_(c_reg);
            // quantize + pack 4 lanes' h into one u32 (unit t -> byte t&3 of word t>>2)
            int q = (int)rintf(fminf(fmaxf(h, -1.0f), 1.0f) * 127.0f) & 0xff;
            int q1 = __shfl_down(q, 1, 64);
            int q2 = __shfl_down(q, 2, 64);
            int q3 = __shfl_down(q, 3, 64);
            if ((t & 3) == 0)
                h8[t >> 2] = (u32)q | ((u32)q1 << 8) | ((u32)q2 << 16) | ((u32)q3 << 24);
            // output head partial
            float p = h * wo;
#pragma unroll
            for (int off = 32; off > 0; off >>= 1) p += __shfl_down(p, off, 64);
            if ((t & 63) == 0) red[t >> 6] = p;
        }
        __syncthreads();                          // (2) h8 + red ready

        if (t == 0) {
            float yf = sigmoidf_(clamp30(red[0] + red[1] + red[2] + red[3] + bo));
            if (mode) ((float*)yv)[(size_t)s * B_ + b] = yf;
            else      ((u16*)yv)[(size_t)s * B_ + b] = f2b(yf);
        }
    }
}

extern "C" void kernel_launch(void* const* d_in, const int* in_sizes, int n_in,
                              void* d_out, int out_size, void* d_ws, size_t ws_size,
                              hipStream_t stream) {
    const void* pw   = d_in[0];   // [B,S,50]
    const void* Wemb = d_in[1];   // [E,50]
    const void* bemb = d_in[2];   // [E]
    const void* Wih  = d_in[3];   // [G,E]
    const void* Whh  = d_in[4];   // [G,H]
    const void* bih  = d_in[5];   // [G]
    const void* bhh  = d_in[6];   // [G]
    const void* Wout = d_in[7];   // [1,H]
    const void* bout = d_in[8];   // [1]
    const void* h0   = d_in[9];   // [B,H]
    const void* c0   = d_in[10];  // [B,H]
    void* y = d_out;              // [S,B]
    (void)d_ws; (void)ws_size;

    sniff_kernel<<<1, 1, 0, stream>>>((const u16*)Wemb);
    transpose_wih<<<(E_ * G_) / 256, 256, 0, stream>>>(Wih);
    prep_wi8<<<G_ / 256, 256, 0, stream>>>(Whh);
    xg_kernel<<<(B_ * S_) / 16, 256, 0, stream>>>(pw, Wemb, bemb, bih, bhh);
    lstm_i8<<<B_, 1024, 0, stream>>>(Wout, bout, h0, c0, y);
}